// Round 6
// baseline (525.928 us; speedup 1.0000x reference)
//
#include <hip/hip_runtime.h>

#define N_ROWS 262144
#define DDIM   256
#define KREF   32
#define WAVES  8                         // waves per block
#define ROWS_PER_BLOCK (WAVES * 16)      // 128
#define GRID_WY (N_ROWS / ROWS_PER_BLOCK)   // 2048 blocks

typedef __attribute__((ext_vector_type(4))) float f32x4;
typedef __attribute__((ext_vector_type(8))) short bf16x8;

// Fragment tables (written by setup kernels).
// g_V*[nt*512 + c*64 + lane] : GEMM1 B = V, elem j = Q[16nt+(lane&15)][32c+8*(lane>>4)+j]
// g_U*[mt*64 + lane]         : GEMM2 A = U, elem j = U[16mt+(lane&15)][8*(lane>>4)+j]
__device__ bf16x8 g_Vhi[2 * 8 * 64];
__device__ bf16x8 g_Vlo[2 * 8 * 64];
__device__ bf16x8 g_Uhi[16 * 64];
__device__ bf16x8 g_Ulo[16 * 64];
__device__ float  g_T[32 * 32];

__device__ __forceinline__ unsigned short f2bf(float x) {   // RNE (setup only)
    unsigned u = __float_as_uint(x);
    u += 0x7fffu + ((u >> 16) & 1u);
    return (unsigned short)(u >> 16);
}
__device__ __forceinline__ float bf2f(unsigned short h) {
    return __uint_as_float(((unsigned)h) << 16);
}

// ---------------------------------------------------------------------------
// setup_a (1 block): G = V^T V, T (larft recurrence), V fragment packing.
// ---------------------------------------------------------------------------
#define QS_LD 264
#define T_LD  33

__global__ __launch_bounds__(256)
void setup_a(const float* __restrict__ Q) {
    __shared__ float Qs[32 * QS_LD];
    __shared__ float G[32 * 32];
    __shared__ float T[32 * T_LD];
    __shared__ float beta[32];
    const int tid = threadIdx.x;

    // Stage Q -> LDS (padded rows)
    {
        const int q  = tid >> 3;
        const int c8 = tid & 7;
        const f32x4* src = (const f32x4*)(Q + q * DDIM);
        f32x4* dst = (f32x4*)(Qs + q * QS_LD);
        #pragma unroll
        for (int i = 0; i < 8; ++i)
            dst[c8 + 8 * i] = src[c8 + 8 * i];
    }
    __syncthreads();

    // G[i][j] = q_i . q_j
    for (int p = tid; p < 1024; p += 256) {
        const int i = p >> 5, j = p & 31;
        const f32x4* qi = (const f32x4*)(Qs + i * QS_LD);
        const f32x4* qj = (const f32x4*)(Qs + j * QS_LD);
        float s = 0.f;
        #pragma unroll 8
        for (int d = 0; d < 64; ++d) {
            const f32x4 a = qi[d], b = qj[d];
            s += a.x * b.x + a.y * b.y + a.z * b.z + a.w * b.w;
        }
        G[p] = s;
    }
    for (int p = tid; p < 32 * T_LD; p += 256) T[p] = 0.f;
    __syncthreads();

    if (tid < 32) beta[tid] = 2.0f / G[tid * 32 + tid];
    __syncthreads();

    // T: forward recurrence for H_1...H_K = I - V T V^T
    for (int k = 0; k < 32; ++k) {
        if (tid < k) {
            float s = 0.f;
            for (int j = tid; j < k; ++j) s += T[tid * T_LD + j] * G[j * 32 + k];
            T[tid * T_LD + k] = -beta[k] * s;
        } else if (tid == k) {
            T[k * T_LD + k] = beta[k];
        }
        __syncthreads();
    }

    // Publish T for setup_b
    for (int p = tid; p < 1024; p += 256)
        g_T[p] = T[(p >> 5) * T_LD + (p & 31)];

    // Pack V fragments (bf16 hi/lo, RNE) from Qs
    for (int e = tid; e < 2 * 8 * 64; e += 256) {
        const int lane = e & 63, c = (e >> 6) & 7, nt = e >> 9;
        const int q  = 16 * nt + (lane & 15);
        const int d0 = 32 * c + 8 * (lane >> 4);
        bf16x8 vh, vl;
        #pragma unroll
        for (int j = 0; j < 8; ++j) {
            const float x = Qs[q * QS_LD + d0 + j];
            const unsigned short h = f2bf(x);
            vh[j] = (short)h;
            vl[j] = (short)f2bf(x - bf2f(h));
        }
        g_Vhi[e] = vh; g_Vlo[e] = vl;
    }
}

// ---------------------------------------------------------------------------
// setup_b (16 blocks): U[d][k] = sum_{j>=k} T[k][j] Q[j][d] for the block's
// 16-wide d slice; pack U fragments for that mt.
// ---------------------------------------------------------------------------
__global__ __launch_bounds__(256)
void setup_b(const float* __restrict__ Q) {
    __shared__ float Ts[32 * 32];
    __shared__ float Us[16 * 33];
    const int tid = threadIdx.x;
    const int m = blockIdx.x;          // mt = 0..15

    for (int p = tid; p < 1024; p += 256) Ts[p] = g_T[p];
    __syncthreads();

    #pragma unroll
    for (int e = 0; e < 2; ++e) {
        const int idx = tid + 256 * e;         // 0..511
        const int dd = idx >> 5, k = idx & 31;
        const int d = 16 * m + dd;
        float s = 0.f;
        for (int j = k; j < 32; ++j) s += Ts[k * 32 + j] * Q[j * DDIM + d];
        Us[dd * 33 + k] = s;
    }
    __syncthreads();

    if (tid < 64) {
        const int dd = tid & 15, k0 = 8 * (tid >> 4);
        bf16x8 uh, ul;
        #pragma unroll
        for (int j = 0; j < 8; ++j) {
            const float x = Us[dd * 33 + k0 + j];
            const unsigned short h = f2bf(x);
            uh[j] = (short)h;
            ul[j] = (short)f2bf(x - bf2f(h));
        }
        g_Uhi[m * 64 + tid] = uh;
        g_Ulo[m * 64 + tid] = ul;
    }
}

// ---------------------------------------------------------------------------
// Main: out = X - (X V)(T V^T).  8 waves/block so the 32 KB V-table LDS cost
// amortizes over 2x the waves: 51.2 KB/block -> 3 blocks/CU = 24 waves/CU
// (vs 12 before). Memory-latency hiding comes from TLP, not in-wave pipelining.
// Truncation-based bf16 hi/lo split (x - hi is exact): ~4 VALU/elem vs ~9.
// ---------------------------------------------------------------------------
__global__ __launch_bounds__(512)
void wy_kernel(const float* __restrict__ X, float* __restrict__ out) {
    __shared__ bf16x8 sVhi[1024];          // 16 KB
    __shared__ bf16x8 sVlo[1024];          // 16 KB
    __shared__ float  tscr[WAVES][16 * 36];   // 18 KB transpose scratch

    const int tid  = threadIdx.x;
    const int wave = tid >> 6;
    const int lane = tid & 63;
    const int t = lane & 15;
    const int g = lane >> 4;

    // Stage V tables -> LDS (coalesced f32x4)
    {
        const f32x4* s1 = (const f32x4*)g_Vhi;
        const f32x4* s2 = (const f32x4*)g_Vlo;
        f32x4* d1 = (f32x4*)sVhi;
        f32x4* d2 = (f32x4*)sVlo;
        #pragma unroll
        for (int i = 0; i < 2; ++i) {
            d1[tid + 512 * i] = s1[tid + 512 * i];
            d2[tid + 512 * i] = s2[tid + 512 * i];
        }
    }
    __syncthreads();

    const int row = blockIdx.x * ROWS_PER_BLOCK + wave * 16 + t;  // lane's A-row
    const float* xp = X + (size_t)row * DDIM + 8 * g;

    // ---- GEMM1: C1 = X_tile . V, k-streamed; 4 independent acc chains ----
    f32x4 a0h = {0.f, 0.f, 0.f, 0.f}, a0l = {0.f, 0.f, 0.f, 0.f};
    f32x4 a1h = {0.f, 0.f, 0.f, 0.f}, a1l = {0.f, 0.f, 0.f, 0.f};
    #pragma unroll
    for (int c = 0; c < 8; ++c) {
        const f32x4 x0 = *(const f32x4*)(xp + 32 * c);
        const f32x4 x1 = *(const f32x4*)(xp + 32 * c + 4);
        bf16x8 ah, al;
        #pragma unroll
        for (int e = 0; e < 8; ++e) {
            const float v = (e < 4) ? x0[e] : x1[e - 4];
            const unsigned u = __float_as_uint(v);
            ah[e] = (short)(u >> 16);                       // truncate -> hi
            const float hi = __uint_as_float(u & 0xffff0000u);
            al[e] = (short)(__float_as_uint(v - hi) >> 16); // exact diff, trunc
        }
        const bf16x8 bh0 = sVhi[c * 64 + lane];
        const bf16x8 bl0 = sVlo[c * 64 + lane];
        const bf16x8 bh1 = sVhi[512 + c * 64 + lane];
        const bf16x8 bl1 = sVlo[512 + c * 64 + lane];
        a0h = __builtin_amdgcn_mfma_f32_16x16x32_bf16(ah, bh0, a0h, 0, 0, 0);
        a0l = __builtin_amdgcn_mfma_f32_16x16x32_bf16(al, bh0, a0l, 0, 0, 0);
        a0l = __builtin_amdgcn_mfma_f32_16x16x32_bf16(ah, bl0, a0l, 0, 0, 0);
        a1h = __builtin_amdgcn_mfma_f32_16x16x32_bf16(ah, bh1, a1h, 0, 0, 0);
        a1l = __builtin_amdgcn_mfma_f32_16x16x32_bf16(al, bh1, a1l, 0, 0, 0);
        a1l = __builtin_amdgcn_mfma_f32_16x16x32_bf16(ah, bl1, a1l, 0, 0, 0);
    }
    const f32x4 acc0 = a0h + a0l;
    const f32x4 acc1 = a1h + a1l;

    // ---- Transpose C1: D-layout -> fragment of -C1^T (wave-private) ----
    float* tb = tscr[wave];
    #pragma unroll
    for (int r = 0; r < 4; ++r) {
        tb[(4 * g + r) * 36 + t]      = acc0[r];
        tb[(4 * g + r) * 36 + 16 + t] = acc1[r];
    }
    asm volatile("s_waitcnt lgkmcnt(0)" ::: "memory");
    __builtin_amdgcn_sched_barrier(0);
    const f32x4 c01 = *(const f32x4*)(tb + t * 36 + 8 * g);
    const f32x4 c23 = *(const f32x4*)(tb + t * 36 + 8 * g + 4);

    bf16x8 chi, clo;
    #pragma unroll
    for (int j = 0; j < 8; ++j) {
        const float v = -((j < 4) ? c01[j] : c23[j - 4]);
        const unsigned u = __float_as_uint(v);
        chi[j] = (short)(u >> 16);
        const float hi = __uint_as_float(u & 0xffff0000u);
        clo[j] = (short)(__float_as_uint(v - hi) >> 16);
    }

    // ---- GEMM2': D = U_tile.(-C1^T) + X ; 16 independent mt chains ----
    const float* xr = X   + (size_t)row * DDIM + 4 * g;
    float*       op = out + (size_t)row * DDIM + 4 * g;
    #pragma unroll
    for (int mt = 0; mt < 16; ++mt) {
        const f32x4 xe = *(const f32x4*)(xr + 16 * mt);   // C operand (cache-hot)
        const bf16x8 uh = g_Uhi[mt * 64 + lane];
        const bf16x8 ul = g_Ulo[mt * 64 + lane];
        f32x4 a = __builtin_amdgcn_mfma_f32_16x16x32_bf16(uh, chi, xe, 0, 0, 0);
        a = __builtin_amdgcn_mfma_f32_16x16x32_bf16(ul, chi, a, 0, 0, 0);
        a = __builtin_amdgcn_mfma_f32_16x16x32_bf16(uh, clo, a, 0, 0, 0);
        *(f32x4*)(op + 16 * mt) = a;
    }

    // logabsdet = zeros(N): 128 rows per block
    if (tid < ROWS_PER_BLOCK)
        out[(size_t)N_ROWS * DDIM + (size_t)blockIdx.x * ROWS_PER_BLOCK + tid] = 0.0f;
}

extern "C" void kernel_launch(void* const* d_in, const int* in_sizes, int n_in,
                              void* d_out, int out_size, void* d_ws, size_t ws_size,
                              hipStream_t stream) {
    const float* X = (const float*)d_in[0];   // [N, D] fp32
    const float* Q = (const float*)d_in[1];   // [K, D] fp32
    float* out = (float*)d_out;               // [N*D + N] fp32

    setup_a<<<1, 256, 0, stream>>>(Q);
    setup_b<<<16, 256, 0, stream>>>(Q);
    wy_kernel<<<GRID_WY, 512, 0, stream>>>(X, out);
}